// Round 10
// baseline (485.904 us; speedup 1.0000x reference)
//
#include <hip/hip_runtime.h>
#include <hip/hip_bf16.h>
#include <stdint.h>

#define BB 8
#define LL 4096
#define DD 64
#define KT 64                // pass-1 k-tile
#define NT (LL / KT)         // 64
#define NP2 (LL / 128)       // 32 pass-2 tiles (128 wide)

typedef short bf16x8 __attribute__((ext_vector_type(8)));
typedef short bf16x2 __attribute__((ext_vector_type(2)));
typedef float f32x4 __attribute__((ext_vector_type(4)));

__device__ inline short f2bfs(float x) {
    __hip_bfloat16 h = __float2bfloat16(x);
    return __builtin_bit_cast(short, h);
}

__device__ inline bf16x8 pack8v(f32x4 a, f32x4 b) {
    bf16x8 r;
    r[0] = f2bfs(a[0]); r[1] = f2bfs(a[1]); r[2] = f2bfs(a[2]); r[3] = f2bfs(a[3]);
    r[4] = f2bfs(b[0]); r[5] = f2bfs(b[1]); r[6] = f2bfs(b[2]); r[7] = f2bfs(b[3]);
    return r;
}

// K rows are visited as r = a*8 + n*4 + b (a=lr>>2, b=lr&3): swzK spreads those.
__device__ inline int swzK(int r) { return (r & 3) | (((r >> 3) & 1) << 2); }
// V rows are visited consecutively: the round-4 swizzle.
__device__ inline int swzV(int r) { return (r & 7) ^ ((r >> 3) & 7); }

__global__ void detect_mask_kernel(const uint32_t* __restrict__ w, uint32_t* __restrict__ flag) {
    __shared__ int nonbin;
    if (threadIdx.x == 0) nonbin = 0;
    __syncthreads();
    int bad = 0;
    for (int i = threadIdx.x; i < 4096; i += 256) bad |= (w[i] > 1u) ? 1 : 0;
    if (bad) atomicOr(&nonbin, 1);
    __syncthreads();
    if (threadIdx.x == 0) *flag = (uint32_t)(nonbin != 0);
}

// One block = 64 q-rows of one batch, 512 threads = 8 waves (rg=w&3, ch=w>>2).
// QK uses permuted K-fragment rows so the C-frag IS the PV A-frag: lane (lr,lg)
// holds P[q=16rg+lr][k = W+lg*8..+7]. P never touches LDS. Pass 1: QK + exp +
// row sums + UNNORMALIZED PV accumulate (flash-style); mask read once (u64/lane),
// bits cached in Msk. Pass 2: streaming QK recompute + attn write (128-wide K
// tiles over all 4 LDS buffers). Final: combine ch-halves of O via LDS, scale 1/l.
__global__ __launch_bounds__(512, 4) void fused_attn_kernel(
    const float* __restrict__ qg, const float* __restrict__ kg,
    const float* __restrict__ vg, const void* __restrict__ maskv,
    const uint32_t* __restrict__ flagp,
    float* __restrict__ attn, float* __restrict__ outp)
{
    __shared__ alignas(16) ushort KB[4][KT * 64];  // 4 x 8 KB: p1 K dbuf={0,1}, V dbuf={2,3}; p2: 128-row K dbuf
    __shared__ uint8_t Msk[8][NT][64];             // mask bits [wave][tile][lane] (32 KB)
    __shared__ float Rs[128];                      // exp row sums [ch][q]

    const int tid = (int)threadIdx.x;
    const int w   = tid >> 6, l = tid & 63;
    const int lr  = l & 15, lg = l >> 4;
    const int rg  = w & 3, ch = w >> 2;
    const int id  = (int)blockIdx.x;     // id = qt*8 + b
    const int b   = id & 7;
    const int q0  = (id >> 3) * 64;
    const bool mbyte = (*flagp != 0);

    const float* kb = kg + (size_t)b * LL * DD;
    const float* vb = vg + (size_t)b * LL * DD;

    const int qrow = q0 + 16 * rg + lr;
    const uint8_t* mrow8  = (const uint8_t*)maskv + (size_t)b * LL * LL + (size_t)qrow * LL + ch * 32 + lg * 8;
    const int*     mrow32 = (const int*)maskv     + (size_t)b * LL * LL + (size_t)qrow * LL + ch * 32 + lg * 8;
    float* arow = attn + (size_t)b * LL * LL + (size_t)qrow * LL + ch * 32 + lg * 8;

    // Q B-fragments, pre-scaled by 1/8
    bf16x8 qf0, qf1;
    {
        const float* qp = qg + (size_t)(b * LL + qrow) * DD + lg * 8;
        qf0 = pack8v(*(const f32x4*)(qp)      * 0.125f, *(const f32x4*)(qp + 4)  * 0.125f);
        qf1 = pack8v(*(const f32x4*)(qp + 32) * 0.125f, *(const f32x4*)(qp + 36) * 0.125f);
    }

    const int krow0 = tid >> 3, kc8 = tid & 7;
    // pass-1 K staging (64 rows)
    f32x4 ka0, ka1;
    auto kiss1 = [&](int kbase) {
        const float* p = kb + (size_t)(kbase + krow0) * DD + kc8 * 8;
        ka0 = *(const f32x4*)p;
        ka1 = *(const f32x4*)(p + 4);
    };
    auto kcom1 = [&](int buf) {
        *(bf16x8*)&KB[buf][krow0 * 64 + ((kc8 ^ swzK(krow0)) << 3)] = pack8v(ka0, ka1);
    };
    // V staging (64 rows, transposed to [d][k])
    const int vk2 = tid >> 4, vd4 = tid & 15;
    f32x4 va0, va1;
    auto viss = [&](int kbase) {
        const float* p = vb + (size_t)(kbase + vk2 * 2) * DD + vd4 * 4;
        va0 = *(const f32x4*)p;
        va1 = *(const f32x4*)(p + DD);
    };
    auto vcom = [&](int buf) {
        const int k0 = vk2 * 2;
        #pragma unroll
        for (int e = 0; e < 4; ++e) {
            const int d = vd4 * 4 + e;
            bf16x2 t;
            t[0] = f2bfs(va0[e]);
            t[1] = f2bfs(va1[e]);
            *(bf16x2*)&KB[2 + buf][d * 64 + (((k0 >> 3) ^ swzV(d)) << 3) + (k0 & 7)] = t;
        }
    };

    // ================= pass 1: sums + unnormalized PV =================
    float rsum = 0.f;
    f32x4 oacc[4];
    #pragma unroll
    for (int g = 0; g < 4; ++g) { f32x4 z = {0.f, 0.f, 0.f, 0.f}; oacc[g] = z; }

    uint64_t mw = 0;
    int4 mi0 = {0,0,0,0}, mi1 = {0,0,0,0};
    if (mbyte) mw = *(const uint64_t*)(mrow8);
    else { mi0 = *(const int4*)(mrow32); mi1 = *(const int4*)(mrow32 + 4); }

    kiss1(0); viss(0);
    kcom1(0); vcom(0);
    __syncthreads();
    #pragma unroll 1
    for (int kt = 0; kt < NT; ++kt) {
        const int cur = kt & 1, kbase = kt * KT;
        const bool more = (kt < NT - 1);
        if (more) { kiss1(kbase + KT); viss(kbase + KT); }
        uint64_t nmw = 0;
        int4 ni0 = {0,0,0,0}, ni1 = {0,0,0,0};
        if (more) {
            if (mbyte) nmw = *(const uint64_t*)(mrow8 + kbase + KT);
            else { ni0 = *(const int4*)(mrow32 + kbase + KT); ni1 = *(const int4*)(mrow32 + kbase + KT + 4); }
        }

        uint32_t mbits = 0;
        float p8[8];
        #pragma unroll
        for (int n = 0; n < 2; ++n) {
            const int krow = ch * 32 + ((lr >> 2) << 3) + (n << 2) + (lr & 3);
            bf16x8 k0 = *(const bf16x8*)&KB[cur][krow * 64 + ((lg       ^ swzK(krow)) << 3)];
            bf16x8 k1 = *(const bf16x8*)&KB[cur][krow * 64 + (((4 + lg) ^ swzK(krow)) << 3)];
            f32x4 c = {0.f, 0.f, 0.f, 0.f};
            c = __builtin_amdgcn_mfma_f32_16x16x32_bf16(k0, qf0, c, 0, 0, 0);
            c = __builtin_amdgcn_mfma_f32_16x16x32_bf16(k1, qf1, c, 0, 0, 0);
            #pragma unroll
            for (int j = 0; j < 4; ++j) {
                const int t = n * 4 + j;
                int mk;
                if (mbyte) mk = (int)((mw >> (8 * t)) & 0xffu);
                else {
                    const int4 mi = n ? mi1 : mi0;
                    mk = (j == 0) ? mi.x : (j == 1) ? mi.y : (j == 2) ? mi.z : mi.w;
                }
                mbits |= (mk ? 1u : 0u) << t;
                const float pv = mk ? 0.f : __expf(c[j]);
                rsum += pv;
                p8[t] = pv;
            }
        }
        Msk[w][kt][l] = (uint8_t)mbits;

        bf16x8 pa;
        #pragma unroll
        for (int t = 0; t < 8; ++t) pa[t] = f2bfs(p8[t]);

        #pragma unroll
        for (int g = 0; g < 4; ++g) {
            const int d = g * 16 + lr;
            bf16x8 vf = *(const bf16x8*)&KB[2 + cur][d * 64 + (((ch * 4 + lg) ^ swzV(d)) << 3)];
            oacc[g] = __builtin_amdgcn_mfma_f32_16x16x32_bf16(pa, vf, oacc[g], 0, 0, 0);
        }

        mw = nmw; mi0 = ni0; mi1 = ni1;
        if (more) { kcom1((kt + 1) & 1); vcom((kt + 1) & 1); }
        __syncthreads();
    }

    rsum += __shfl_xor(rsum, 16, 64);
    rsum += __shfl_xor(rsum, 32, 64);
    if (lg == 0) Rs[ch * 64 + 16 * rg + lr] = rsum;
    __syncthreads();
    const float rinv = 1.0f / (Rs[16 * rg + lr] + Rs[64 + 16 * rg + lr]);

    // ================= pass 2: streaming attn write (128-wide K tiles) =================
    f32x4 kA[4];
    auto kiss2 = [&](int kbase) {
        #pragma unroll
        for (int m = 0; m < 2; ++m) {
            const float* p = kb + (size_t)(kbase + krow0 + 64 * m) * DD + kc8 * 8;
            kA[2 * m]     = *(const f32x4*)p;
            kA[2 * m + 1] = *(const f32x4*)(p + 4);
        }
    };
    auto kcom2 = [&](int pair) {
        #pragma unroll
        for (int m = 0; m < 2; ++m)
            *(bf16x8*)&KB[2 * pair + m][krow0 * 64 + ((kc8 ^ swzK(krow0)) << 3)] = pack8v(kA[2 * m], kA[2 * m + 1]);
    };

    kiss2(0); kcom2(0);
    __syncthreads();
    #pragma unroll 1
    for (int kt2 = 0; kt2 < NP2; ++kt2) {
        const int pair = kt2 & 1, kbase2 = kt2 * 128;
        const bool more = (kt2 < NP2 - 1);
        if (more) kiss2(kbase2 + 128);
        #pragma unroll
        for (int h = 0; h < 2; ++h) {
            const int mb = (int)Msk[w][2 * kt2 + h][l];
            const ushort* Kbuf = KB[2 * pair + h];
            #pragma unroll
            for (int n = 0; n < 2; ++n) {
                const int krow = ch * 32 + ((lr >> 2) << 3) + (n << 2) + (lr & 3);
                bf16x8 k0 = *(const bf16x8*)&Kbuf[krow * 64 + ((lg       ^ swzK(krow)) << 3)];
                bf16x8 k1 = *(const bf16x8*)&Kbuf[krow * 64 + (((4 + lg) ^ swzK(krow)) << 3)];
                f32x4 c = {0.f, 0.f, 0.f, 0.f};
                c = __builtin_amdgcn_mfma_f32_16x16x32_bf16(k0, qf0, c, 0, 0, 0);
                c = __builtin_amdgcn_mfma_f32_16x16x32_bf16(k1, qf1, c, 0, 0, 0);
                f32x4 pv;
                #pragma unroll
                for (int j = 0; j < 4; ++j)
                    pv[j] = ((mb >> (n * 4 + j)) & 1) ? 0.f : __expf(c[j]) * rinv;
                __builtin_nontemporal_store(pv, (f32x4*)(arow + kbase2 + h * 64 + n * 4));
            }
        }
        if (more) kcom2((kt2 + 1) & 1);
        __syncthreads();
    }

    // ================= epilogue: combine ch halves of O, scale, write =================
    float* OutL = (float*)KB;    // 17.4 KB (stride 68) inside the 32 KB KB region
    if (ch == 1) {
        #pragma unroll
        for (int g = 0; g < 4; ++g)
            #pragma unroll
            for (int j = 0; j < 4; ++j)
                OutL[rg * 1088 + (lg * 4 + j) * 68 + g * 16 + lr] = oacc[g][j];
    }
    __syncthreads();
    if (ch == 0) {
        #pragma unroll
        for (int j = 0; j < 4; ++j) {
            const int ql = 16 * rg + lg * 4 + j;
            const float ri = 1.0f / (Rs[ql] + Rs[64 + ql]);
            const size_t orow = (size_t)(b * LL + q0 + ql) * DD;
            #pragma unroll
            for (int g = 0; g < 4; ++g) {
                const float o = (oacc[g][j] + OutL[rg * 1088 + (lg * 4 + j) * 68 + g * 16 + lr]) * ri;
                __builtin_nontemporal_store(o, &outp[orow + g * 16 + lr]);
            }
        }
    }
}

extern "C" void kernel_launch(void* const* d_in, const int* in_sizes, int n_in,
                              void* d_out, int out_size, void* d_ws, size_t ws_size,
                              hipStream_t stream) {
    const float* q = (const float*)d_in[0];
    const float* k = (const float*)d_in[1];
    const float* v = (const float*)d_in[2];
    const void* mask = d_in[3];
    float* attn = (float*)d_out;
    float* outp = attn + (size_t)BB * LL * LL;
    uint32_t* flagp = (uint32_t*)d_ws;

    detect_mask_kernel<<<1, 256, 0, stream>>>((const uint32_t*)mask, flagp);
    fused_attn_kernel<<<dim3((LL / 64) * BB), 512, 0, stream>>>(q, k, v, mask, flagp, attn, outp);
}

// Round 11
// 379.908 us; speedup vs baseline: 1.2790x; 1.2790x over previous
//
#include <hip/hip_runtime.h>
#include <hip/hip_bf16.h>
#include <stdint.h>

#define BB 8
#define LL 4096
#define DD 64
#define KT 64                // pass-1 k-tile
#define NT (LL / KT)         // 64
#define NP2 (LL / 128)       // 32 pass-2 tiles (128 wide)

typedef short bf16x8 __attribute__((ext_vector_type(8)));
typedef short bf16x2 __attribute__((ext_vector_type(2)));
typedef float f32x4 __attribute__((ext_vector_type(4)));

__device__ inline short f2bfs(float x) {
    __hip_bfloat16 h = __float2bfloat16(x);
    return __builtin_bit_cast(short, h);
}

__device__ inline bf16x8 pack8v(f32x4 a, f32x4 b) {
    bf16x8 r;
    r[0] = f2bfs(a[0]); r[1] = f2bfs(a[1]); r[2] = f2bfs(a[2]); r[3] = f2bfs(a[3]);
    r[4] = f2bfs(b[0]); r[5] = f2bfs(b[1]); r[6] = f2bfs(b[2]); r[7] = f2bfs(b[3]);
    return r;
}

__device__ inline int swzK(int r) { return (r & 3) | (((r >> 3) & 1) << 2); }
__device__ inline int swzV(int r) { return (r & 7) ^ ((r >> 3) & 7); }

// Raw barrier WITHOUT the __syncthreads vmcnt(0) drain: own ds ops flushed,
// prefetch global loads stay in flight across the barrier (T3/T4-lite).
__device__ inline void wg_barrier() {
    asm volatile("s_waitcnt lgkmcnt(0)" ::: "memory");
    __builtin_amdgcn_s_barrier();
    __builtin_amdgcn_sched_barrier(0);
}

__global__ void detect_mask_kernel(const uint32_t* __restrict__ w, uint32_t* __restrict__ flag) {
    __shared__ int nonbin;
    if (threadIdx.x == 0) nonbin = 0;
    __syncthreads();
    int bad = 0;
    for (int i = threadIdx.x; i < 4096; i += 256) bad |= (w[i] > 1u) ? 1 : 0;
    if (bad) atomicOr(&nonbin, 1);
    __syncthreads();
    if (threadIdx.x == 0) *flag = (uint32_t)(nonbin != 0);
}

// One block = 64 q-rows of one batch, 512 threads = 8 waves (rg=w&3, ch=w>>2).
// Permuted-K QK (mfma(K,Q)) makes the C-frag identical to the PV A-frag, so P
// stays in registers. Pass 1: QK + exp + rowsum + unnormalized PV (flash-style);
// mask read once, bits cached in Msk LDS. Pass 2: QK recompute + normalized
// attn write (plain f32x4 stores -- nontemporal caused 2x write amplification).
// Both loops: 2-deep A/B register prefetch + raw barriers (no vmcnt(0) drain).
__global__ __launch_bounds__(512, 4) void fused_attn_kernel(
    const float* __restrict__ qg, const float* __restrict__ kg,
    const float* __restrict__ vg, const void* __restrict__ maskv,
    const uint32_t* __restrict__ flagp,
    float* __restrict__ attn, float* __restrict__ outp)
{
    __shared__ alignas(16) ushort KB[4][KT * 64];  // p1: K dbuf {0,1}, V^T dbuf {2,3}; p2: two 128-row K pairs
    __shared__ uint8_t Msk[8][NT][64];             // mask bits [wave][tile][lane] (32 KB)
    __shared__ float Rs[128];                      // exp row sums [ch][q]

    const int tid = (int)threadIdx.x;
    const int w   = tid >> 6, l = tid & 63;
    const int lr  = l & 15, lg = l >> 4;
    const int rg  = w & 3, ch = w >> 2;
    const int id  = (int)blockIdx.x;     // id = qt*8 + b
    const int b   = id & 7;
    const int q0  = (id >> 3) * 64;
    const bool mbyte = (*flagp != 0);

    const float* kb = kg + (size_t)b * LL * DD;
    const float* vb = vg + (size_t)b * LL * DD;

    const int qrow = q0 + 16 * rg + lr;
    const uint8_t* mrow8  = (const uint8_t*)maskv + (size_t)b * LL * LL + (size_t)qrow * LL + ch * 32 + lg * 8;
    const int*     mrow32 = (const int*)maskv     + (size_t)b * LL * LL + (size_t)qrow * LL + ch * 32 + lg * 8;
    float* arow = attn + (size_t)b * LL * LL + (size_t)qrow * LL + ch * 32 + lg * 8;

    // Q B-fragments, pre-scaled by 1/8
    bf16x8 qf0, qf1;
    {
        const float* qp = qg + (size_t)(b * LL + qrow) * DD + lg * 8;
        qf0 = pack8v(*(const f32x4*)(qp)      * 0.125f, *(const f32x4*)(qp + 4)  * 0.125f);
        qf1 = pack8v(*(const f32x4*)(qp + 32) * 0.125f, *(const f32x4*)(qp + 36) * 0.125f);
    }

    const int krow0 = tid >> 3, kc8 = tid & 7;
    const int vk2 = tid >> 4, vd4 = tid & 15;

    // ---------- pass-1 prefetch register sets (A/B) ----------
    f32x4 kA0, kA1, vA0, vA1; uint64_t mA = 0;
    f32x4 kB0, kB1, vB0, vB1; uint64_t mB = 0;
    auto issA = [&](int kt) {
        const int kbase = kt * KT;
        const float* p = kb + (size_t)(kbase + krow0) * DD + kc8 * 8;
        kA0 = *(const f32x4*)p; kA1 = *(const f32x4*)(p + 4);
        const float* pv = vb + (size_t)(kbase + vk2 * 2) * DD + vd4 * 4;
        vA0 = *(const f32x4*)pv; vA1 = *(const f32x4*)(pv + DD);
        if (mbyte) mA = *(const uint64_t*)(mrow8 + kbase);
    };
    auto issB = [&](int kt) {
        const int kbase = kt * KT;
        const float* p = kb + (size_t)(kbase + krow0) * DD + kc8 * 8;
        kB0 = *(const f32x4*)p; kB1 = *(const f32x4*)(p + 4);
        const float* pv = vb + (size_t)(kbase + vk2 * 2) * DD + vd4 * 4;
        vB0 = *(const f32x4*)pv; vB1 = *(const f32x4*)(pv + DD);
        if (mbyte) mB = *(const uint64_t*)(mrow8 + kbase);
    };
    auto comA = [&](int buf) {
        *(bf16x8*)&KB[buf][krow0 * 64 + ((kc8 ^ swzK(krow0)) << 3)] = pack8v(kA0, kA1);
        const int k0 = vk2 * 2;
        #pragma unroll
        for (int e = 0; e < 4; ++e) {
            const int d = vd4 * 4 + e;
            bf16x2 t; t[0] = f2bfs(vA0[e]); t[1] = f2bfs(vA1[e]);
            *(bf16x2*)&KB[2 + buf][d * 64 + (((k0 >> 3) ^ swzV(d)) << 3) + (k0 & 7)] = t;
        }
    };
    auto comB = [&](int buf) {
        *(bf16x8*)&KB[buf][krow0 * 64 + ((kc8 ^ swzK(krow0)) << 3)] = pack8v(kB0, kB1);
        const int k0 = vk2 * 2;
        #pragma unroll
        for (int e = 0; e < 4; ++e) {
            const int d = vd4 * 4 + e;
            bf16x2 t; t[0] = f2bfs(vB0[e]); t[1] = f2bfs(vB1[e]);
            *(bf16x2*)&KB[2 + buf][d * 64 + (((k0 >> 3) ^ swzV(d)) << 3) + (k0 & 7)] = t;
        }
    };

    // ================= pass 1: sums + unnormalized PV =================
    float rsum = 0.f;
    f32x4 oacc[4];
    #pragma unroll
    for (int g = 0; g < 4; ++g) { f32x4 z = {0.f, 0.f, 0.f, 0.f}; oacc[g] = z; }

    auto p1body = [&](int buf, uint64_t mu, int kt) {
        const int kbase = kt * KT;
        int4 mi0 = {0,0,0,0}, mi1 = {0,0,0,0};
        if (!mbyte) { mi0 = *(const int4*)(mrow32 + kbase); mi1 = *(const int4*)(mrow32 + kbase + 4); }
        uint32_t mbits = 0;
        float p8[8];
        #pragma unroll
        for (int n = 0; n < 2; ++n) {
            const int krow = ch * 32 + ((lr >> 2) << 3) + (n << 2) + (lr & 3);
            bf16x8 k0 = *(const bf16x8*)&KB[buf][krow * 64 + ((lg       ^ swzK(krow)) << 3)];
            bf16x8 k1 = *(const bf16x8*)&KB[buf][krow * 64 + (((4 + lg) ^ swzK(krow)) << 3)];
            f32x4 c = {0.f, 0.f, 0.f, 0.f};
            c = __builtin_amdgcn_mfma_f32_16x16x32_bf16(k0, qf0, c, 0, 0, 0);
            c = __builtin_amdgcn_mfma_f32_16x16x32_bf16(k1, qf1, c, 0, 0, 0);
            #pragma unroll
            for (int j = 0; j < 4; ++j) {
                const int t = n * 4 + j;
                int mk;
                if (mbyte) mk = (int)((mu >> (8 * t)) & 0xffu);
                else {
                    const int4 mi = n ? mi1 : mi0;
                    mk = (j == 0) ? mi.x : (j == 1) ? mi.y : (j == 2) ? mi.z : mi.w;
                }
                mbits |= (mk ? 1u : 0u) << t;
                const float pv = mk ? 0.f : __expf(c[j]);
                rsum += pv;
                p8[t] = pv;
            }
        }
        Msk[w][kt][l] = (uint8_t)mbits;
        bf16x8 pa;
        #pragma unroll
        for (int t = 0; t < 8; ++t) pa[t] = f2bfs(p8[t]);
        __builtin_amdgcn_s_setprio(1);
        #pragma unroll
        for (int g = 0; g < 4; ++g) {
            const int d = g * 16 + lr;
            bf16x8 vf = *(const bf16x8*)&KB[2 + buf][d * 64 + (((ch * 4 + lg) ^ swzV(d)) << 3)];
            oacc[g] = __builtin_amdgcn_mfma_f32_16x16x32_bf16(pa, vf, oacc[g], 0, 0, 0);
        }
        __builtin_amdgcn_s_setprio(0);
    };

    issA(0); issB(1);
    comA(0);
    wg_barrier();
    #pragma unroll 1
    for (int kt = 0; kt < NT; kt += 2) {
        {   // even tile kt -> buf0; prefetch kt+2 into A; commit B (kt+1) -> buf1
            const uint64_t mu = mA;
            if (kt + 2 < NT) issA(kt + 2);
            p1body(0, mu, kt);
            comB(1);
            wg_barrier();
        }
        {   // odd tile kt+1 -> buf1; prefetch kt+3 into B; commit A (kt+2) -> buf0
            const uint64_t mu = mB;
            if (kt + 3 < NT) issB(kt + 3);
            p1body(1, mu, kt + 1);
            if (kt + 2 < NT) comA(0);
            wg_barrier();
        }
    }

    rsum += __shfl_xor(rsum, 16, 64);
    rsum += __shfl_xor(rsum, 32, 64);
    if (lg == 0) Rs[ch * 64 + 16 * rg + lr] = rsum;
    __syncthreads();
    const float rinv = 1.0f / (Rs[16 * rg + lr] + Rs[64 + 16 * rg + lr]);

    // ================= pass 2: streaming attn write (128-wide tiles) =================
    f32x4 k2A[4], k2B[4];
    auto iss2A = [&](int kt2) {
        #pragma unroll
        for (int m = 0; m < 2; ++m) {
            const float* p = kb + (size_t)(kt2 * 128 + krow0 + 64 * m) * DD + kc8 * 8;
            k2A[2 * m]     = *(const f32x4*)p;
            k2A[2 * m + 1] = *(const f32x4*)(p + 4);
        }
    };
    auto iss2B = [&](int kt2) {
        #pragma unroll
        for (int m = 0; m < 2; ++m) {
            const float* p = kb + (size_t)(kt2 * 128 + krow0 + 64 * m) * DD + kc8 * 8;
            k2B[2 * m]     = *(const f32x4*)p;
            k2B[2 * m + 1] = *(const f32x4*)(p + 4);
        }
    };
    auto com2A = [&](int pair) {
        #pragma unroll
        for (int m = 0; m < 2; ++m)
            *(bf16x8*)&KB[2 * pair + m][krow0 * 64 + ((kc8 ^ swzK(krow0)) << 3)] = pack8v(k2A[2 * m], k2A[2 * m + 1]);
    };
    auto com2B = [&](int pair) {
        #pragma unroll
        for (int m = 0; m < 2; ++m)
            *(bf16x8*)&KB[2 * pair + m][krow0 * 64 + ((kc8 ^ swzK(krow0)) << 3)] = pack8v(k2B[2 * m], k2B[2 * m + 1]);
    };
    auto p2body = [&](int pair, int idx) {
        const int kbase2 = idx * 128;
        #pragma unroll
        for (int h = 0; h < 2; ++h) {
            const int mb2 = (int)Msk[w][2 * idx + h][l];
            const ushort* Kbuf = KB[2 * pair + h];
            #pragma unroll
            for (int n = 0; n < 2; ++n) {
                const int krow = ch * 32 + ((lr >> 2) << 3) + (n << 2) + (lr & 3);
                bf16x8 k0 = *(const bf16x8*)&Kbuf[krow * 64 + ((lg       ^ swzK(krow)) << 3)];
                bf16x8 k1 = *(const bf16x8*)&Kbuf[krow * 64 + (((4 + lg) ^ swzK(krow)) << 3)];
                f32x4 c = {0.f, 0.f, 0.f, 0.f};
                c = __builtin_amdgcn_mfma_f32_16x16x32_bf16(k0, qf0, c, 0, 0, 0);
                c = __builtin_amdgcn_mfma_f32_16x16x32_bf16(k1, qf1, c, 0, 0, 0);
                f32x4 pv;
                #pragma unroll
                for (int j = 0; j < 4; ++j)
                    pv[j] = ((mb2 >> (n * 4 + j)) & 1) ? 0.f : __expf(c[j]) * rinv;
                *(f32x4*)(arow + kbase2 + h * 64 + n * 4) = pv;   // plain store: L2 merges
            }
        }
    };

    iss2A(0); iss2B(1);
    com2A(0);
    wg_barrier();
    #pragma unroll 1
    for (int kt2 = 0; kt2 < NP2; kt2 += 2) {
        if (kt2 + 2 < NP2) iss2A(kt2 + 2);
        p2body(0, kt2);
        com2B(1);
        wg_barrier();
        if (kt2 + 3 < NP2) iss2B(kt2 + 3);
        p2body(1, kt2 + 1);
        if (kt2 + 2 < NP2) com2A(0);
        wg_barrier();
    }

    // ================= epilogue: combine ch halves of O, scale, write =================
    float* OutL = (float*)KB;    // reuse retired KB region (17.4 KB, stride 68)
    if (ch == 1) {
        #pragma unroll
        for (int g = 0; g < 4; ++g)
            #pragma unroll
            for (int j = 0; j < 4; ++j)
                OutL[rg * 1088 + (lg * 4 + j) * 68 + g * 16 + lr] = oacc[g][j];
    }
    __syncthreads();
    if (ch == 0) {
        #pragma unroll
        for (int j = 0; j < 4; ++j) {
            const int ql = 16 * rg + lg * 4 + j;
            const float ri = 1.0f / (Rs[ql] + Rs[64 + ql]);
            const size_t orow = (size_t)(b * LL + q0 + ql) * DD;
            #pragma unroll
            for (int g = 0; g < 4; ++g) {
                const float o = (oacc[g][j] + OutL[rg * 1088 + (lg * 4 + j) * 68 + g * 16 + lr]) * ri;
                outp[orow + g * 16 + lr] = o;
            }
        }
    }
}

extern "C" void kernel_launch(void* const* d_in, const int* in_sizes, int n_in,
                              void* d_out, int out_size, void* d_ws, size_t ws_size,
                              hipStream_t stream) {
    const float* q = (const float*)d_in[0];
    const float* k = (const float*)d_in[1];
    const float* v = (const float*)d_in[2];
    const void* mask = d_in[3];
    float* attn = (float*)d_out;
    float* outp = attn + (size_t)BB * LL * LL;
    uint32_t* flagp = (uint32_t*)d_ws;

    detect_mask_kernel<<<1, 256, 0, stream>>>((const uint32_t*)mask, flagp);
    fused_attn_kernel<<<dim3((LL / 64) * BB), 512, 0, stream>>>(q, k, v, mask, flagp, attn, outp);
}